// Round 10
// baseline (203.011 us; speedup 1.0000x reference)
//
#include <hip/hip_runtime.h>

typedef unsigned short u16;
typedef __attribute__((ext_vector_type(8))) short bf16x8;
typedef __attribute__((ext_vector_type(4))) float f32x4;

__device__ __forceinline__ float bf2f(u16 u) {
  union { unsigned u; float f; } c; c.u = ((unsigned)u) << 16; return c.f;
}
__device__ __forceinline__ u16 f2bf(float f) {
  union { float f; unsigned u; } c; c.f = f;
  unsigned u = c.u;
  return (u16)((u + 0x7FFFu + ((u >> 16) & 1u)) >> 16);
}
// async global->LDS, 16B per lane; LDS dest = wave-uniform base + lane*16
__device__ __forceinline__ void gld16(const void* g, void* l) {
  __builtin_amdgcn_global_load_lds(
      (__attribute__((address_space(1))) void*)g,
      (__attribute__((address_space(3))) void*)l, 16, 0, 0);
}

// full-drain barrier (used in wave-role-divergent attn; counts matched
// across roles). sched_barrier stops hipcc hoisting across the waitcnt.
#define SYNCB() do { \
  asm volatile("s_waitcnt vmcnt(0) lgkmcnt(0)" ::: "memory"); \
  __builtin_amdgcn_s_barrier(); \
  __builtin_amdgcn_sched_barrier(0); \
} while (0)

#define BB 32      // batch
#define CC 256     // channels
#define NN 1024    // H*W

// ---------------- 0. BatchNorm stats: per-channel mean/var -> scale/shift ----
__global__ __launch_bounds__(256) void bn_stats_kernel(
    const float* __restrict__ x, const float* __restrict__ gamma,
    const float* __restrict__ beta, float* __restrict__ scl, float* __restrict__ sft)
{
  int c = blockIdx.x;
  int tid = threadIdx.x;
  float s = 0.f, q = 0.f;
  for (int g = tid; g < 8192; g += 256) {
    int b = g >> 8;
    int n = (g & 255) * 4;
    float4 v = *reinterpret_cast<const float4*>(x + (((size_t)(b * CC + c)) << 10) + n);
    s += v.x + v.y + v.z + v.w;
    q += v.x * v.x + v.y * v.y + v.z * v.z + v.w * v.w;
  }
  __shared__ float rs[256], rq[256];
  rs[tid] = s; rq[tid] = q;
  __syncthreads();
  for (int off = 128; off > 0; off >>= 1) {
    if (tid < off) { rs[tid] += rs[tid + off]; rq[tid] += rq[tid + off]; }
    __syncthreads();
  }
  if (tid == 0) {
    float mean = rs[0] * (1.f / 32768.f);
    float var  = rq[0] * (1.f / 32768.f) - mean * mean;
    float rstd = rsqrtf(var + 1e-5f);
    float g = gamma[c] * rstd;
    scl[c] = g;
    sft[c] = beta[c] - mean * g;
  }
}

// ---------------- 1. weight prep: fold BN into Wkqv -------------------------
// t@W^T + b  ==  x@(W*scl)^T + (b + W.sft)   (per-channel scl/sft)
__global__ __launch_bounds__(256) void prep_w_kernel(
    const float* __restrict__ Wk, const float* __restrict__ bk,
    const float* __restrict__ Wp, const float* __restrict__ bp,
    const float* __restrict__ scl, const float* __restrict__ sft,
    u16* __restrict__ Wkb, float* __restrict__ bkbf,
    u16* __restrict__ Wpb, float* __restrict__ bpbf)
{
  int o = blockIdx.x, c = threadIdx.x;
  __shared__ float red[256];
  if (o < 768) {
    float w = Wk[o * 256 + c];
    Wkb[o * 256 + c] = f2bf(w * scl[c]);
    red[c] = w * sft[c];
    __syncthreads();
    for (int off = 128; off > 0; off >>= 1) {
      if (c < off) red[c] += red[c + off];
      __syncthreads();
    }
    if (c == 0) bkbf[o] = bk[o] + red[0];
  } else {
    int op = o - 768;
    Wpb[op * 256 + c] = f2bf(Wp[op * 256 + c]);
    if (c == 0) bpbf[op] = bp[op];
  }
}

// ---------------- 2. fused QKV GEMM on raw x (BN folded into W') ------------
// (round-8 proven) SW-pipelined, counted vmcnt(8), 2 barriers/step.
__global__ __launch_bounds__(256, 2) void qkv_fused_kernel(
    const float* __restrict__ x, const u16* __restrict__ Wkb,
    const float* __restrict__ bkbf, u16* __restrict__ qkout, u16* __restrict__ vt)
{
  __shared__ __align__(16) u16 As[2][128 * 32];   // 2x8 KB, 16B-swizzled
  __shared__ __align__(16) u16 Bs[2][256 * 32];   // 2x16 KB, linear (gld16)
  int bid = blockIdx.x;
  int bx = bid & 255, by = bid >> 8;           // by = 0..2
  int b = bx >> 3, nsp0 = (bx & 7) * 128;
  int tid = threadIdx.x, lane = tid & 63, w = tid >> 6;
  int lq = lane & 15, quad = lane >> 4;
  int wm = (w >> 1) * 64, wn = (w & 1) * 128;
  int ar = lane >> 2, ac = (lane & 3) * 8;     // B staging: 4 lanes/row, 16B
  int rbB = w * 64;                            // wave's 64-row B slice
  int nn4 = (tid & 31) * 4;                    // A staging: 4 n-rows
  int c8i = tid >> 5;                          // 8B-chunk index (0..7)
  int cg  = c8i * 4;                           // 4 c-cols

  const float* xb = x + (((size_t)(b * CC)) << 10) + nsp0 + nn4;
  const u16* Bw = Wkb + (size_t)(by * 256) * 256;

  f32x4 zero = {0.f, 0.f, 0.f, 0.f};
  f32x4 acc[4][8];
  #pragma unroll
  for (int i = 0; i < 4; ++i)
    #pragma unroll
    for (int j = 0; j < 8; ++j) acc[i][j] = zero;

  // ---- prologue: first prefetches (8 VMEM ops) ----
  float4 xA[4], xB[4];
  #pragma unroll
  for (int i = 0; i < 4; ++i)
    gld16(Bw + (size_t)(rbB + i * 16 + ar) * 256 + ac, &Bs[0][(rbB + i * 16) * 32]);
  #pragma unroll
  for (int ci = 0; ci < 4; ++ci)
    xA[ci] = *reinterpret_cast<const float4*>(xb + ((size_t)(cg + ci) << 10));

  auto body = [&](int t, float4 (&xc)[4], float4 (&xn)[4]) {
    int k0 = t * 32;
    if (t < 7) {
      int kn = k0 + 32;
      #pragma unroll
      for (int i = 0; i < 4; ++i)
        gld16(Bw + (size_t)(rbB + i * 16 + ar) * 256 + kn + ac,
              &Bs[(t + 1) & 1][(rbB + i * 16) * 32]);
      #pragma unroll
      for (int ci = 0; ci < 4; ++ci)
        xn[ci] = *reinterpret_cast<const float4*>(xb + ((size_t)(kn + cg + ci) << 10));
    }
    if (t < 7) {
      asm volatile("s_waitcnt vmcnt(8)" ::: "memory");  // tile t done; t+1 in flight
    } else {
      asm volatile("s_waitcnt vmcnt(0)" ::: "memory");
    }
    __builtin_amdgcn_sched_barrier(0);
    u16 av[4][4];
    #pragma unroll
    for (int ci = 0; ci < 4; ++ci) {
      av[ci][0] = f2bf(xc[ci].x);
      av[ci][1] = f2bf(xc[ci].y);
      av[ci][2] = f2bf(xc[ci].z);
      av[ci][3] = f2bf(xc[ci].w);
    }
    int c16 = c8i >> 1, lo8 = (c8i & 1) * 4;
    #pragma unroll
    for (int ni = 0; ni < 4; ++ni) {
      int n = nn4 + ni;
      int s2 = (n >> 2) & 3;
      ushort4 o4;
      o4.x = av[0][ni]; o4.y = av[1][ni]; o4.z = av[2][ni]; o4.w = av[3][ni];
      *reinterpret_cast<ushort4*>(
          &As[t & 1][n * 32 + ((c16 ^ s2) * 8 + lo8)]) = o4;
    }
    asm volatile("s_waitcnt lgkmcnt(0)" ::: "memory");   // ds_writes visible
    __builtin_amdgcn_s_barrier();                        // B1: tile-t staged
    __builtin_amdgcn_sched_barrier(0);

    bf16x8 af[4], bfr[8];
    #pragma unroll
    for (int i = 0; i < 4; ++i) {
      int r = wm + i * 16 + lq;
      af[i] = *reinterpret_cast<const bf16x8*>(
          &As[t & 1][r * 32 + ((quad ^ ((r >> 2) & 3)) * 8)]);
    }
    #pragma unroll
    for (int j = 0; j < 8; ++j)
      bfr[j] = *reinterpret_cast<const bf16x8*>(
          &Bs[t & 1][(wn + j * 16 + lq) * 32 + quad * 8]);
    __builtin_amdgcn_s_setprio(1);
    #pragma unroll
    for (int i = 0; i < 4; ++i)
      #pragma unroll
      for (int j = 0; j < 8; ++j)
        acc[i][j] = __builtin_amdgcn_mfma_f32_16x16x32_bf16(af[i], bfr[j], acc[i][j], 0, 0, 0);
    __builtin_amdgcn_s_setprio(0);
    asm volatile("s_waitcnt lgkmcnt(0)" ::: "memory");   // own frag reads done
    __builtin_amdgcn_s_barrier();                        // B2: buffers reusable
    __builtin_amdgcn_sched_barrier(0);
  };

  #pragma unroll 1
  for (int tt = 0; tt < 4; ++tt) {
    body(2 * tt,     xA, xB);
    body(2 * tt + 1, xB, xA);
  }

  if (by < 2) {
    #pragma unroll
    for (int j = 0; j < 8; ++j) {
      int col = by * 256 + wn + j * 16 + lq;
      float bv = bkbf[col];
      #pragma unroll
      for (int i = 0; i < 4; ++i) {
        int m = (b << 10) + nsp0 + wm + i * 16 + quad * 4;
        #pragma unroll
        for (int r = 0; r < 4; ++r)
          qkout[(size_t)(m + r) * 512 + col] = f2bf(acc[i][j][r] + bv);
      }
    }
  } else {
    #pragma unroll
    for (int j = 0; j < 8; ++j) {
      int col = wn + j * 16 + lq;
      float bv = bkbf[512 + col];
      #pragma unroll
      for (int i = 0; i < 4; ++i) {
        int n = nsp0 + wm + i * 16 + quad * 4;
        ushort4 o;
        o.x = f2bf(acc[i][j][0] + bv);
        o.y = f2bf(acc[i][j][1] + bv);
        o.z = f2bf(acc[i][j][2] + bv);
        o.w = f2bf(acc[i][j][3] + bv);
        *reinterpret_cast<ushort4*>(&vt[(size_t)b * 262144 + (size_t)col * 1024 + n]) = o;
      }
    }
  }
}

// ---------------- 3. NT bf16 GEMM (proj + residual) -------------------------
__global__ __launch_bounds__(256) void gemm_nt_kernel(
    const u16* __restrict__ A, int lda, size_t sA,
    const u16* __restrict__ B, int ldb, size_t sB,
    u16* __restrict__ C, int ldc, size_t sC,
    int K, const float* __restrict__ bias, float scale, int mode,
    const float* __restrict__ xres, float* __restrict__ outf)
{
  __shared__ u16 As[128 * 32];   // unpadded: global_load_lds needs lane-contiguous
  __shared__ u16 Bs[128 * 32];
  int tid = threadIdx.x;
  int m0 = blockIdx.x * 128, n0 = blockIdx.y * 128;
  const u16* Ab = A + (size_t)blockIdx.z * sA;
  const u16* Bb = B + (size_t)blockIdx.z * sB;
  u16* Cb = C + (size_t)blockIdx.z * sC;

  int lane = tid & 63, w = tid >> 6;
  int lq = lane & 15, quad = lane >> 4;
  int wm = (w >> 1) * 64, wn = (w & 1) * 64;
  int ar = lane >> 2, ac = (lane & 3) * 8;   // staging: 4 lanes/row, 16B each
  int rb = w * 32;                            // wave's 32-row staging slice

  f32x4 zero = {0.f, 0.f, 0.f, 0.f};
  f32x4 acc[4][4];
  #pragma unroll
  for (int i = 0; i < 4; ++i)
    #pragma unroll
    for (int j = 0; j < 4; ++j) acc[i][j] = zero;

  for (int k0 = 0; k0 < K; k0 += 32) {
    __syncthreads();   // previous tile's ds_reads complete before overwrite
    gld16(Ab + (size_t)(m0 + rb +      ar) * lda + k0 + ac, &As[(rb     ) * 32]);
    gld16(Ab + (size_t)(m0 + rb + 16 + ar) * lda + k0 + ac, &As[(rb + 16) * 32]);
    gld16(Bb + (size_t)(n0 + rb +      ar) * ldb + k0 + ac, &Bs[(rb     ) * 32]);
    gld16(Bb + (size_t)(n0 + rb + 16 + ar) * ldb + k0 + ac, &Bs[(rb + 16) * 32]);
    __syncthreads();   // compiler drains vmcnt before barrier
    bf16x8 af[4], bfr[4];
    #pragma unroll
    for (int i = 0; i < 4; ++i) {
      af[i]  = *reinterpret_cast<const bf16x8*>(&As[(wm + i * 16 + lq) * 32 + quad * 8]);
      bfr[i] = *reinterpret_cast<const bf16x8*>(&Bs[(wn + i * 16 + lq) * 32 + quad * 8]);
    }
    #pragma unroll
    for (int i = 0; i < 4; ++i)
      #pragma unroll
      for (int j = 0; j < 4; ++j)
        acc[i][j] = __builtin_amdgcn_mfma_f32_16x16x32_bf16(af[i], bfr[j], acc[i][j], 0, 0, 0);
  }

  #pragma unroll
  for (int j = 0; j < 4; ++j) {
    int col = n0 + wn + j * 16 + lq;
    float bv = bias ? bias[col] : 0.f;
    #pragma unroll
    for (int i = 0; i < 4; ++i) {
      int rbase = m0 + wm + i * 16 + quad * 4;
      if (mode == 2) {
        int b = rbase >> 10, n = rbase & 1023;
        size_t idx = (((size_t)(b * CC + col)) << 10) + n;
        float4 xv = *reinterpret_cast<const float4*>(xres + idx);
        float4 o;
        o.x = acc[i][j][0] * scale + bv + xv.x;
        o.y = acc[i][j][1] * scale + bv + xv.y;
        o.z = acc[i][j][2] * scale + bv + xv.z;
        o.w = acc[i][j][3] * scale + bv + xv.w;
        *reinterpret_cast<float4*>(outf + idx) = o;
      } else {
        #pragma unroll
        for (int r = 0; r < 4; ++r)
          Cb[(size_t)(rbase + r) * ldc + col] = f2bf(acc[i][j][r] * scale + bv);
      }
    }
  }
}

// ---------------- 4. fused attention: O = softmax(Q K^T / 16) V -------------
// Half-size blocks for 2 blocks/CU (inter-block TLP): 64 q-rows per block,
// KV-tile = 32 key positions, 68 KB LDS. Same proven 8-wave role split and
// full-drain barrier protocol as round 6:
//   waves 0-3 (QK): 16 q-rows each, Q in regs; S(p) -> exp -> P between the
//   two phase barriers.  waves 4-7 (PV): 64 rows x 64 out-cols; O += P(p-1)V(p-1).
// Two independent blocks per CU interleave: one block's barrier stall is
// covered by the other block's compute (the m114 mechanism; intra-block
// waves could not provide this because barriers sync them all).
// 64-B LDS rows (V, P) use chunk ^ ((row>>1)&3) (row&7 would escape the
// 4-chunk row; residual 2-way aliasing is free).
__global__ __launch_bounds__(512, 4) void attn_kernel(
    const u16* __restrict__ qk,   // [B*1024, 512]: Q = cols 0:256, K = 256:512
    const u16* __restrict__ vt,   // [B, 256, 1024]: V^T per batch
    u16* __restrict__ o)          // [B*1024, 256]
{
  __shared__ __align__(16) u16 Ks[2][32 * 256];   // 2x16 KB [kcol][c], chunk^=(r&7)
  __shared__ __align__(16) u16 Vs[2][256 * 32];   // 2x16 KB [d][k], chunk^=((d>>1)&3)
  __shared__ __align__(16) u16 Ps[64 * 32];       // 4 KB [q][kcol], chunk^=((q>>1)&3)
  float* rs = (float*)Ps;          // 64 f32 inv-rowsums; alias ok: P dead then

  int bid = blockIdx.x;            // 512 blocks: 32 batches x 16 64-row tiles
  // XCD swizzle: batch b fixed per (bid&31) -> all q-tiles of ~4 batches/XCD
  int b  = (bid & 7) + 8 * ((bid >> 3) & 3);
  int qt = bid >> 5;               // 0..15
  int tid = threadIdx.x, lane = tid & 63, w = tid >> 6;
  int lq = lane & 15, hh = lane >> 4;
  int wr = w & 3;                  // QK: row-16 group.  PV: col-64 group
  bool isQK = w < 4;

  const u16* qb = qk + ((size_t)b << 10) * 512;
  const u16* kb = qb + 256;
  const u16* vb = vt + ((size_t)b << 18);

  // staging: 512 threads, 2 chunks(16B) each per tile (1024 chunks = 16 KB)
  auto stageK = [&](int kt, int bufi) {
    #pragma unroll
    for (int i = 0; i < 2; ++i) {
      int slot = i * 512 + tid;
      int r = slot >> 5, c = slot & 31;          // 32 chunks per 512B row
      gld16(kb + (size_t)(kt * 32 + r) * 512 + ((c ^ (r & 7)) << 3),
            &Ks[bufi][(i * 512 + (tid & 448)) * 8]);
    }
  };
  auto stageV = [&](int kt, int bufi) {
    #pragma unroll
    for (int i = 0; i < 2; ++i) {
      int slot = i * 512 + tid;
      int n = slot >> 2, c = slot & 3;           // 4 chunks per 64B row
      gld16(vb + (size_t)(n << 10) + kt * 32 + ((c ^ ((n >> 1) & 3)) << 3),
            &Vs[bufi][(i * 512 + (tid & 448)) * 8]);
    }
  };

  f32x4 zero = {0.f, 0.f, 0.f, 0.f};

  // prologue: stage K(0) into buf0 (common, uniform)
  stageK(0, 0);
  SYNCB();                                   // barrier #1

  if (isQK) {
    // ---------------- QK / softmax producer (16 rows/wave) ----------------
    int q0 = qt * 64 + wr * 16;
    bf16x8 qf[8];
    #pragma unroll
    for (int kk = 0; kk < 8; ++kk)
      qf[kk] = *reinterpret_cast<const bf16x8*>(
          qb + (size_t)(q0 + lq) * 512 + kk * 32 + hh * 8);
    float runsum[4] = {0.f, 0.f, 0.f, 0.f};

    #pragma unroll 1
    for (int p = 0; p <= 32; ++p) {
      if (p <= 31) stageV(p, p & 1);
      if (p <= 30) stageK(p + 1, (p + 1) & 1);
      u16 pbv[2][4];
      if (p <= 31) {
        const u16* Kc = Ks[p & 1];
        f32x4 sacc[2];
        sacc[0] = zero; sacc[1] = zero;
        #pragma unroll
        for (int kk = 0; kk < 8; ++kk) {
          bf16x8 kf[2];
          #pragma unroll
          for (int ni = 0; ni < 2; ++ni) {
            int r = ni * 16 + lq;
            kf[ni] = *reinterpret_cast<const bf16x8*>(
                &Kc[r * 256 + (((kk * 4 + hh) ^ (r & 7)) << 3)]);
          }
          __builtin_amdgcn_s_setprio(1);
          #pragma unroll
          for (int ni = 0; ni < 2; ++ni)
            sacc[ni] = __builtin_amdgcn_mfma_f32_16x16x32_bf16(
                qf[kk], kf[ni], sacc[ni], 0, 0, 0);
          __builtin_amdgcn_s_setprio(0);
        }
        // softmax numerator into regs (write deferred past barrier A)
        #pragma unroll
        for (int ni = 0; ni < 2; ++ni)
          #pragma unroll
          for (int rr = 0; rr < 4; ++rr) {
            float pexp = __expf(sacc[ni][rr] * 0.0625f);
            u16 pb = f2bf(pexp);
            runsum[rr] += bf2f(pb);   // sum rounded values (= PV input)
            pbv[ni][rr] = pb;
          }
      }
      SYNCB();                               // phase barrier A
      if (p <= 31) {
        #pragma unroll
        for (int ni = 0; ni < 2; ++ni)
          #pragma unroll
          for (int rr = 0; rr < 4; ++rr) {
            int q = wr * 16 + hh * 4 + rr;
            int kcol = ni * 16 + lq;
            Ps[q * 32 + ((((kcol >> 3) ^ ((q >> 1) & 3)) << 3) | (kcol & 7))] =
                pbv[ni][rr];
          }
      }
      SYNCB();                               // phase barrier B
    }

    // inv-rowsums -> LDS for the PV waves
    #pragma unroll
    for (int rr = 0; rr < 4; ++rr) {
      float s = runsum[rr];
      s += __shfl_xor(s, 1, 64);
      s += __shfl_xor(s, 2, 64);
      s += __shfl_xor(s, 4, 64);
      s += __shfl_xor(s, 8, 64);
      if (lq == 0) rs[wr * 16 + hh * 4 + rr] = 1.f / s;
    }
    SYNCB();                                 // final barrier
  } else {
    // ---------------- PV consumer (64 rows x 64 cols per wave) -------------
    int wc = wr * 64;                        // output-channel quarter
    f32x4 oacc[4][4];
    #pragma unroll
    for (int qi = 0; qi < 4; ++qi)
      #pragma unroll
      for (int nj = 0; nj < 4; ++nj) oacc[qi][nj] = zero;

    #pragma unroll 1
    for (int p = 0; p <= 32; ++p) {
      if (p <= 31) stageV(p, p & 1);
      if (p <= 30) stageK(p + 1, (p + 1) & 1);
      if (p >= 1) {
        const u16* Vc = Vs[(p - 1) & 1];
        bf16x8 pa[4], vf[4];
        #pragma unroll
        for (int qi = 0; qi < 4; ++qi) {
          int r = qi * 16 + lq;
          pa[qi] = *reinterpret_cast<const bf16x8*>(
              &Ps[r * 32 + ((hh ^ ((r >> 1) & 3)) << 3)]);
        }
        #pragma unroll
        for (int nj = 0; nj < 4; ++nj) {
          int n = wc + nj * 16 + lq;
          vf[nj] = *reinterpret_cast<const bf16x8*>(
              &Vc[n * 32 + ((hh ^ ((n >> 1) & 3)) << 3)]);
        }
        __builtin_amdgcn_s_setprio(1);
        #pragma unroll
        for (int qi = 0; qi < 4; ++qi)
          #pragma unroll
          for (int nj = 0; nj < 4; ++nj)
            oacc[qi][nj] = __builtin_amdgcn_mfma_f32_16x16x32_bf16(
                pa[qi], vf[nj], oacc[qi][nj], 0, 0, 0);
        __builtin_amdgcn_s_setprio(0);
      }
      SYNCB();                               // phase barrier A
      SYNCB();                               // phase barrier B
    }

    SYNCB();                                 // final barrier (rowsums ready)
    float rinv[4][4];
    #pragma unroll
    for (int qi = 0; qi < 4; ++qi)
      #pragma unroll
      for (int rr = 0; rr < 4; ++rr)
        rinv[qi][rr] = rs[qi * 16 + hh * 4 + rr];
    u16* ob = o + ((size_t)(b << 10) + qt * 64) * 256;
    #pragma unroll
    for (int qi = 0; qi < 4; ++qi)
      #pragma unroll
      for (int nj = 0; nj < 4; ++nj)
        #pragma unroll
        for (int rr = 0; rr < 4; ++rr)
          ob[(size_t)(qi * 16 + hh * 4 + rr) * 256 + wc + nj * 16 + lq] =
              f2bf(oacc[qi][nj][rr] * rinv[qi][rr]);
  }
}

extern "C" void kernel_launch(void* const* d_in, const int* in_sizes, int n_in,
                              void* d_out, int out_size, void* d_ws, size_t ws_size,
                              hipStream_t stream) {
  const float* x     = (const float*)d_in[0];
  const float* gamma = (const float*)d_in[1];
  const float* beta  = (const float*)d_in[2];
  const float* Wkqv  = (const float*)d_in[3];
  const float* bkqv  = (const float*)d_in[4];
  const float* Wproj = (const float*)d_in[5];
  const float* bproj = (const float*)d_in[6];
  float* out = (float*)d_out;          // fp32 [32,256,32,32]

  // ---- workspace layout ----
  char* ws = (char*)d_ws;
  float* scl  = (float*)ws;                     // 256 f32
  float* sft  = (float*)(ws + 1024);            // 256 f32
  u16* Wkb    = (u16*)(ws + 4096);              // 196608 bf16 (BN-folded)
  u16* Wpb    = (u16*)(ws + 397312);            // 65536 bf16
  float* bkbf = (float*)(ws + 528384);          // 768 f32 (folded bias)
  float* bpbf = (float*)(ws + 531456);          // 256 f32
  u16* qk   = (u16*)(ws + 1048576);             // [32768,512] bf16 = 32 MB
  u16* vt   = qk + (size_t)32768 * 512;         // [32,256,1024] bf16 = 16 MB
  u16* o_pv = vt + (size_t)32 * 256 * 1024;     // [32768,256] bf16 = 16 MB

  // 0. BN stats (must precede weight prep: scl/sft feed the fold)
  bn_stats_kernel<<<dim3(256), dim3(256), 0, stream>>>(x, gamma, beta, scl, sft);
  // 1. weight prep: W' = Wkqv*scl (bf16), b' = b + Wkqv.sft (fp32); Wp plain
  prep_w_kernel<<<dim3(1024), dim3(256), 0, stream>>>(
      Wkqv, bkqv, Wproj, bproj, scl, sft, Wkb, bkbf, Wpb, bpbf);
  // 2. fused QKV GEMM on raw x (SW-pipelined, vectorized staging): qk + vt
  qkv_fused_kernel<<<dim3(768), dim3(256), 0, stream>>>(
      x, Wkb, bkbf, qk, vt);
  // 3. fused attention (half blocks, 2/CU inter-block TLP): o_pv (bf16)
  attn_kernel<<<dim3(512), dim3(512), 0, stream>>>(qk, vt, o_pv);
  // 4. fused proj + residual: out[b,c,n] = (o_pv @ Wproj^T + bproj)[n,c] + x[b,c,n]
  gemm_nt_kernel<<<dim3(256, 2, 1), dim3(256), 0, stream>>>(
      o_pv, 256, 0, Wpb, 256, 0, nullptr, 0, 0, 256, bpbf, 1.0f, 2, x, out);
}

// Round 11
// 195.101 us; speedup vs baseline: 1.0405x; 1.0405x over previous
//
#include <hip/hip_runtime.h>

typedef unsigned short u16;
typedef __attribute__((ext_vector_type(8))) short bf16x8;
typedef __attribute__((ext_vector_type(4))) float f32x4;

__device__ __forceinline__ float bf2f(u16 u) {
  union { unsigned u; float f; } c; c.u = ((unsigned)u) << 16; return c.f;
}
__device__ __forceinline__ u16 f2bf(float f) {
  union { float f; unsigned u; } c; c.f = f;
  unsigned u = c.u;
  return (u16)((u + 0x7FFFu + ((u >> 16) & 1u)) >> 16);
}
// async global->LDS, 16B per lane; LDS dest = wave-uniform base + lane*16
__device__ __forceinline__ void gld16(const void* g, void* l) {
  __builtin_amdgcn_global_load_lds(
      (__attribute__((address_space(1))) void*)g,
      (__attribute__((address_space(3))) void*)l, 16, 0, 0);
}

// full-drain barrier (used in wave-role-divergent attn; counts matched
// across roles). sched_barrier stops hipcc hoisting across the waitcnt.
#define SYNCB() do { \
  asm volatile("s_waitcnt vmcnt(0) lgkmcnt(0)" ::: "memory"); \
  __builtin_amdgcn_s_barrier(); \
  __builtin_amdgcn_sched_barrier(0); \
} while (0)

#define BB 32      // batch
#define CC 256     // channels
#define NN 1024    // H*W

// ---------------- 0. BatchNorm partial stats (8 blocks/channel) -------------
// 2048 blocks = 256 channels x 8 batch-slices; 8 blocks/CU so HBM latency is
// hidden by TLP (old 256-block version was 1 wave/SIMD, latency-bound).
// Partials accumulated via atomicAdd into ssum/qsum (zeroed by memset).
__global__ __launch_bounds__(256) void bn_stats_kernel(
    const float* __restrict__ x, float* __restrict__ ssum, float* __restrict__ qsum)
{
  int bid = blockIdx.x;
  int c = bid & 255, slice = bid >> 8;     // slice = 4-batch group
  int tid = threadIdx.x;
  float4 v[4];
  #pragma unroll
  for (int i = 0; i < 4; ++i) {
    int g = i * 256 + tid;                 // 0..1023 over 4 batches x 256 n-grps
    int b = slice * 4 + (g >> 8);
    int n = (g & 255) * 4;
    v[i] = *reinterpret_cast<const float4*>(x + (((size_t)(b * CC + c)) << 10) + n);
  }
  float s = 0.f, q = 0.f;
  #pragma unroll
  for (int i = 0; i < 4; ++i) {
    s += v[i].x + v[i].y + v[i].z + v[i].w;
    q += v[i].x * v[i].x + v[i].y * v[i].y + v[i].z * v[i].z + v[i].w * v[i].w;
  }
  // wave reduce (64 lanes) then cross-wave via LDS
  #pragma unroll
  for (int off = 32; off > 0; off >>= 1) {
    s += __shfl_down(s, off, 64);
    q += __shfl_down(q, off, 64);
  }
  __shared__ float rs[4], rq[4];
  int w = tid >> 6, lane = tid & 63;
  if (lane == 0) { rs[w] = s; rq[w] = q; }
  __syncthreads();
  if (tid == 0) {
    float st = rs[0] + rs[1] + rs[2] + rs[3];
    float qt = rq[0] + rq[1] + rq[2] + rq[3];
    atomicAdd(&ssum[c], st);
    atomicAdd(&qsum[c], qt);
  }
}

// ---------------- 1. weight prep: finalize stats + fold BN into Wkqv --------
// scl/sft computed inline from ssum/qsum (each block redundantly: cheap).
// t@W^T + b  ==  x@(W*scl)^T + (b + W.sft)
__global__ __launch_bounds__(256) void prep_w_kernel(
    const float* __restrict__ Wk, const float* __restrict__ bk,
    const float* __restrict__ Wp, const float* __restrict__ bp,
    const float* __restrict__ gamma, const float* __restrict__ beta,
    const float* __restrict__ ssum, const float* __restrict__ qsum,
    u16* __restrict__ Wkb, float* __restrict__ bkbf,
    u16* __restrict__ Wpb, float* __restrict__ bpbf)
{
  int o = blockIdx.x, c = threadIdx.x;
  __shared__ float red[256];
  if (o < 768) {
    float mean = ssum[c] * (1.f / 32768.f);
    float var  = qsum[c] * (1.f / 32768.f) - mean * mean;
    float rstd = rsqrtf(var + 1e-5f);
    float g    = gamma[c] * rstd;
    float sftc = beta[c] - mean * g;
    float w = Wk[o * 256 + c];
    Wkb[o * 256 + c] = f2bf(w * g);
    red[c] = w * sftc;
    __syncthreads();
    for (int off = 128; off > 0; off >>= 1) {
      if (c < off) red[c] += red[c + off];
      __syncthreads();
    }
    if (c == 0) bkbf[o] = bk[o] + red[0];
  } else {
    int op = o - 768;
    Wpb[op * 256 + c] = f2bf(Wp[op * 256 + c]);
    if (c == 0) bpbf[op] = bp[op];
  }
}

// ---------------- 2. fused QKV GEMM on raw x (BN folded into W') ------------
// (round-8 proven) SW-pipelined, counted vmcnt(8), 2 barriers/step.
__global__ __launch_bounds__(256, 2) void qkv_fused_kernel(
    const float* __restrict__ x, const u16* __restrict__ Wkb,
    const float* __restrict__ bkbf, u16* __restrict__ qkout, u16* __restrict__ vt)
{
  __shared__ __align__(16) u16 As[2][128 * 32];   // 2x8 KB, 16B-swizzled
  __shared__ __align__(16) u16 Bs[2][256 * 32];   // 2x16 KB, linear (gld16)
  int bid = blockIdx.x;
  int bx = bid & 255, by = bid >> 8;           // by = 0..2
  int b = bx >> 3, nsp0 = (bx & 7) * 128;
  int tid = threadIdx.x, lane = tid & 63, w = tid >> 6;
  int lq = lane & 15, quad = lane >> 4;
  int wm = (w >> 1) * 64, wn = (w & 1) * 128;
  int ar = lane >> 2, ac = (lane & 3) * 8;     // B staging: 4 lanes/row, 16B
  int rbB = w * 64;                            // wave's 64-row B slice
  int nn4 = (tid & 31) * 4;                    // A staging: 4 n-rows
  int c8i = tid >> 5;                          // 8B-chunk index (0..7)
  int cg  = c8i * 4;                           // 4 c-cols

  const float* xb = x + (((size_t)(b * CC)) << 10) + nsp0 + nn4;
  const u16* Bw = Wkb + (size_t)(by * 256) * 256;

  f32x4 zero = {0.f, 0.f, 0.f, 0.f};
  f32x4 acc[4][8];
  #pragma unroll
  for (int i = 0; i < 4; ++i)
    #pragma unroll
    for (int j = 0; j < 8; ++j) acc[i][j] = zero;

  // ---- prologue: first prefetches (8 VMEM ops) ----
  float4 xA[4], xB[4];
  #pragma unroll
  for (int i = 0; i < 4; ++i)
    gld16(Bw + (size_t)(rbB + i * 16 + ar) * 256 + ac, &Bs[0][(rbB + i * 16) * 32]);
  #pragma unroll
  for (int ci = 0; ci < 4; ++ci)
    xA[ci] = *reinterpret_cast<const float4*>(xb + ((size_t)(cg + ci) << 10));

  auto body = [&](int t, float4 (&xc)[4], float4 (&xn)[4]) {
    int k0 = t * 32;
    if (t < 7) {
      int kn = k0 + 32;
      #pragma unroll
      for (int i = 0; i < 4; ++i)
        gld16(Bw + (size_t)(rbB + i * 16 + ar) * 256 + kn + ac,
              &Bs[(t + 1) & 1][(rbB + i * 16) * 32]);
      #pragma unroll
      for (int ci = 0; ci < 4; ++ci)
        xn[ci] = *reinterpret_cast<const float4*>(xb + ((size_t)(kn + cg + ci) << 10));
    }
    if (t < 7) {
      asm volatile("s_waitcnt vmcnt(8)" ::: "memory");  // tile t done; t+1 in flight
    } else {
      asm volatile("s_waitcnt vmcnt(0)" ::: "memory");
    }
    __builtin_amdgcn_sched_barrier(0);
    u16 av[4][4];
    #pragma unroll
    for (int ci = 0; ci < 4; ++ci) {
      av[ci][0] = f2bf(xc[ci].x);
      av[ci][1] = f2bf(xc[ci].y);
      av[ci][2] = f2bf(xc[ci].z);
      av[ci][3] = f2bf(xc[ci].w);
    }
    int c16 = c8i >> 1, lo8 = (c8i & 1) * 4;
    #pragma unroll
    for (int ni = 0; ni < 4; ++ni) {
      int n = nn4 + ni;
      int s2 = (n >> 2) & 3;
      ushort4 o4;
      o4.x = av[0][ni]; o4.y = av[1][ni]; o4.z = av[2][ni]; o4.w = av[3][ni];
      *reinterpret_cast<ushort4*>(
          &As[t & 1][n * 32 + ((c16 ^ s2) * 8 + lo8)]) = o4;
    }
    asm volatile("s_waitcnt lgkmcnt(0)" ::: "memory");   // ds_writes visible
    __builtin_amdgcn_s_barrier();                        // B1: tile-t staged
    __builtin_amdgcn_sched_barrier(0);

    bf16x8 af[4], bfr[8];
    #pragma unroll
    for (int i = 0; i < 4; ++i) {
      int r = wm + i * 16 + lq;
      af[i] = *reinterpret_cast<const bf16x8*>(
          &As[t & 1][r * 32 + ((quad ^ ((r >> 2) & 3)) * 8)]);
    }
    #pragma unroll
    for (int j = 0; j < 8; ++j)
      bfr[j] = *reinterpret_cast<const bf16x8*>(
          &Bs[t & 1][(wn + j * 16 + lq) * 32 + quad * 8]);
    __builtin_amdgcn_s_setprio(1);
    #pragma unroll
    for (int i = 0; i < 4; ++i)
      #pragma unroll
      for (int j = 0; j < 8; ++j)
        acc[i][j] = __builtin_amdgcn_mfma_f32_16x16x32_bf16(af[i], bfr[j], acc[i][j], 0, 0, 0);
    __builtin_amdgcn_s_setprio(0);
    asm volatile("s_waitcnt lgkmcnt(0)" ::: "memory");   // own frag reads done
    __builtin_amdgcn_s_barrier();                        // B2: buffers reusable
    __builtin_amdgcn_sched_barrier(0);
  };

  #pragma unroll 1
  for (int tt = 0; tt < 4; ++tt) {
    body(2 * tt,     xA, xB);
    body(2 * tt + 1, xB, xA);
  }

  if (by < 2) {
    #pragma unroll
    for (int j = 0; j < 8; ++j) {
      int col = by * 256 + wn + j * 16 + lq;
      float bv = bkbf[col];
      #pragma unroll
      for (int i = 0; i < 4; ++i) {
        int m = (b << 10) + nsp0 + wm + i * 16 + quad * 4;
        #pragma unroll
        for (int r = 0; r < 4; ++r)
          qkout[(size_t)(m + r) * 512 + col] = f2bf(acc[i][j][r] + bv);
      }
    }
  } else {
    #pragma unroll
    for (int j = 0; j < 8; ++j) {
      int col = wn + j * 16 + lq;
      float bv = bkbf[512 + col];
      #pragma unroll
      for (int i = 0; i < 4; ++i) {
        int n = nsp0 + wm + i * 16 + quad * 4;
        ushort4 o;
        o.x = f2bf(acc[i][j][0] + bv);
        o.y = f2bf(acc[i][j][1] + bv);
        o.z = f2bf(acc[i][j][2] + bv);
        o.w = f2bf(acc[i][j][3] + bv);
        *reinterpret_cast<ushort4*>(&vt[(size_t)b * 262144 + (size_t)col * 1024 + n]) = o;
      }
    }
  }
}

// ---------------- 3. proj + residual GEMM, SW-pipelined ---------------------
// out[(b*256+col)<<10 | n] = sum_k o_pv[m,k]*Wp[col,k] + bias[col] + x[...]
// Counted-vmcnt pipeline (ported from the proven qkv structure):
//   top: issue tile t+1's 4 gld16; wait vmcnt(4); B1; 16 MFMA; lgkm(0)+B2.
__global__ __launch_bounds__(256, 2) void proj_kernel(
    const u16* __restrict__ A, const u16* __restrict__ Bw,
    const float* __restrict__ bias, const float* __restrict__ xres,
    float* __restrict__ outf)
{
  __shared__ __align__(16) u16 As[2][128 * 32];   // 2x8 KB, linear (gld16)
  __shared__ __align__(16) u16 Bs[2][128 * 32];   // 2x8 KB, linear (gld16)
  int tid = threadIdx.x;
  int m0 = blockIdx.x * 128, n0 = blockIdx.y * 128;
  int lane = tid & 63, w = tid >> 6;
  int lq = lane & 15, quad = lane >> 4;
  int wm = (w >> 1) * 64, wn = (w & 1) * 64;
  int ar = lane >> 2, ac = (lane & 3) * 8;   // staging: 4 lanes/row, 16B each
  int rb = w * 32;                            // wave's 32-row staging slice

  f32x4 zero = {0.f, 0.f, 0.f, 0.f};
  f32x4 acc[4][4];
  #pragma unroll
  for (int i = 0; i < 4; ++i)
    #pragma unroll
    for (int j = 0; j < 4; ++j) acc[i][j] = zero;

  auto stage = [&](int k0, int bufi) {
    gld16(A  + (size_t)(m0 + rb +      ar) * 256 + k0 + ac, &As[bufi][(rb     ) * 32]);
    gld16(A  + (size_t)(m0 + rb + 16 + ar) * 256 + k0 + ac, &As[bufi][(rb + 16) * 32]);
    gld16(Bw + (size_t)(n0 + rb +      ar) * 256 + k0 + ac, &Bs[bufi][(rb     ) * 32]);
    gld16(Bw + (size_t)(n0 + rb + 16 + ar) * 256 + k0 + ac, &Bs[bufi][(rb + 16) * 32]);
  };

  stage(0, 0);                                // prologue: tile 0 in flight

  #pragma unroll 1
  for (int t = 0; t < 8; ++t) {
    if (t < 7) stage((t + 1) * 32, (t + 1) & 1);
    if (t < 7) {
      asm volatile("s_waitcnt vmcnt(4)" ::: "memory");   // tile t retired
    } else {
      asm volatile("s_waitcnt vmcnt(0)" ::: "memory");
    }
    __builtin_amdgcn_sched_barrier(0);
    __builtin_amdgcn_s_barrier();             // B1: all waves' tile-t loads in
    __builtin_amdgcn_sched_barrier(0);
    bf16x8 af[4], bfr[4];
    #pragma unroll
    for (int i = 0; i < 4; ++i) {
      af[i]  = *reinterpret_cast<const bf16x8*>(&As[t & 1][(wm + i * 16 + lq) * 32 + quad * 8]);
      bfr[i] = *reinterpret_cast<const bf16x8*>(&Bs[t & 1][(wn + i * 16 + lq) * 32 + quad * 8]);
    }
    __builtin_amdgcn_s_setprio(1);
    #pragma unroll
    for (int i = 0; i < 4; ++i)
      #pragma unroll
      for (int j = 0; j < 4; ++j)
        acc[i][j] = __builtin_amdgcn_mfma_f32_16x16x32_bf16(af[i], bfr[j], acc[i][j], 0, 0, 0);
    __builtin_amdgcn_s_setprio(0);
    asm volatile("s_waitcnt lgkmcnt(0)" ::: "memory");   // own frag reads done
    __builtin_amdgcn_s_barrier();             // B2: buffers reusable
    __builtin_amdgcn_sched_barrier(0);
  }

  #pragma unroll
  for (int j = 0; j < 4; ++j) {
    int col = n0 + wn + j * 16 + lq;
    float bv = bias[col];
    #pragma unroll
    for (int i = 0; i < 4; ++i) {
      int rbase = m0 + wm + i * 16 + quad * 4;
      int b = rbase >> 10, n = rbase & 1023;
      size_t idx = (((size_t)(b * CC + col)) << 10) + n;
      float4 xv = *reinterpret_cast<const float4*>(xres + idx);
      float4 o;
      o.x = acc[i][j][0] + bv + xv.x;
      o.y = acc[i][j][1] + bv + xv.y;
      o.z = acc[i][j][2] + bv + xv.z;
      o.w = acc[i][j][3] + bv + xv.w;
      *reinterpret_cast<float4*>(outf + idx) = o;
    }
  }
}

// ---------------- 4. fused attention: O = softmax(Q K^T / 16) V -------------
// (round-6 proven version, best measured 52.5 us) Producer/consumer wave
// specialization: 8 waves. Waves 0-3 (QK): 32 q-rows each, Q in regs;
// S(p) -> exp -> P between the two phase barriers. Waves 4-7 (PV): 64
// output-cols each x all 128 rows; O += P(p-1) * V(p-1).
// K/V double-buffered (gld16, pre-swizzled source), P single-buffered with
// 2-barrier handoff. Matched barrier counts across roles.
__global__ __launch_bounds__(512, 2) void attn_kernel(
    const u16* __restrict__ qk,   // [B*1024, 512]: Q = cols 0:256, K = 256:512
    const u16* __restrict__ vt,   // [B, 256, 1024]: V^T per batch
    u16* __restrict__ o)          // [B*1024, 256]
{
  __shared__ __align__(16) u16 Ks[2][64 * 256];   // 2x32 KB [kr][c], chunk^=(kr&7)
  __shared__ __align__(16) u16 Vs[2][256 * 64];   // 2x32 KB [n][k],  chunk^=(n&7)
  __shared__ __align__(16) u16 Ps[128 * 64];      // 16 KB   [q][k],  chunk^=(q&7)
  float* rs = (float*)Ps;          // 128 f32 inv-rowsums; alias ok: P dead then

  int bid = blockIdx.x;
  // XCD swizzle: all 8 q-tiles of one batch land on one XCD (K/V L2-resident)
  int b  = (bid & 7) + 8 * ((bid >> 3) & 3);
  int qt = bid >> 5;
  int tid = threadIdx.x, lane = tid & 63, w = tid >> 6;
  int lq = lane & 15, hh = lane >> 4;
  int wr = w & 3;                  // row-group (QK) / col-group (PV)
  bool isQK = w < 4;

  const u16* qb = qk + ((size_t)b << 10) * 512;
  const u16* kb = qb + 256;
  const u16* vb = vt + ((size_t)b << 18);

  // staging: 512 threads, 4 chunks(16B) each per tile half
  auto stageK = [&](int kt, int bufi) {
    #pragma unroll
    for (int i = 0; i < 4; ++i) {
      int slot = i * 512 + tid;
      int r = slot >> 5, c = slot & 31;
      gld16(kb + (size_t)(kt * 64 + r) * 512 + ((c ^ (r & 7)) << 3),
            &Ks[bufi][(i * 512 + (tid & 448)) * 8]);
    }
  };
  auto stageV = [&](int kt, int bufi) {
    #pragma unroll
    for (int i = 0; i < 4; ++i) {
      int slot = i * 512 + tid;
      int n = slot >> 3, c = slot & 7;
      gld16(vb + (size_t)(n << 10) + kt * 64 + ((c ^ (n & 7)) << 3),
            &Vs[bufi][(i * 512 + (tid & 448)) * 8]);
    }
  };

  f32x4 zero = {0.f, 0.f, 0.f, 0.f};

  // prologue: stage K(0) into buf0 (common, uniform)
  stageK(0, 0);
  SYNCB();                                   // barrier #1

  if (isQK) {
    // ---------------- QK / softmax producer ----------------
    int q0 = qt * 128 + wr * 32;
    bf16x8 qf[2][8];
    #pragma unroll
    for (int qi = 0; qi < 2; ++qi)
      #pragma unroll
      for (int kk = 0; kk < 8; ++kk)
        qf[qi][kk] = *reinterpret_cast<const bf16x8*>(
            qb + (size_t)(q0 + qi * 16 + lq) * 512 + kk * 32 + hh * 8);
    float runsum[2][4] = {{0.f, 0.f, 0.f, 0.f}, {0.f, 0.f, 0.f, 0.f}};

    #pragma unroll 1
    for (int p = 0; p <= 16; ++p) {
      if (p <= 15) stageV(p, p & 1);
      if (p <= 14) stageK(p + 1, (p + 1) & 1);
      u16 pbv[2][4][4];
      if (p <= 15) {
        const u16* Kc = Ks[p & 1];
        f32x4 sacc[2][4];
        #pragma unroll
        for (int qi = 0; qi < 2; ++qi)
          #pragma unroll
          for (int ni = 0; ni < 4; ++ni) sacc[qi][ni] = zero;
        #pragma unroll
        for (int kk = 0; kk < 8; ++kk) {
          bf16x8 kf[4];
          #pragma unroll
          for (int ni = 0; ni < 4; ++ni) {
            int r = ni * 16 + lq;
            kf[ni] = *reinterpret_cast<const bf16x8*>(
                &Kc[r * 256 + (((kk * 4 + hh) ^ (r & 7)) << 3)]);
          }
          __builtin_amdgcn_s_setprio(1);
          #pragma unroll
          for (int qi = 0; qi < 2; ++qi)
            #pragma unroll
            for (int ni = 0; ni < 4; ++ni)
              sacc[qi][ni] = __builtin_amdgcn_mfma_f32_16x16x32_bf16(
                  qf[qi][kk], kf[ni], sacc[qi][ni], 0, 0, 0);
          __builtin_amdgcn_s_setprio(0);
        }
        // softmax numerator into regs (write deferred past barrier A)
        #pragma unroll
        for (int qi = 0; qi < 2; ++qi)
          #pragma unroll
          for (int ni = 0; ni < 4; ++ni)
            #pragma unroll
            for (int rr = 0; rr < 4; ++rr) {
              float pexp = __expf(sacc[qi][ni][rr] * 0.0625f);
              u16 pb = f2bf(pexp);
              runsum[qi][rr] += bf2f(pb);   // sum rounded values (= PV input)
              pbv[qi][ni][rr] = pb;
            }
      }
      SYNCB();                               // phase barrier A
      if (p <= 15) {
        #pragma unroll
        for (int qi = 0; qi < 2; ++qi)
          #pragma unroll
          for (int ni = 0; ni < 4; ++ni)
            #pragma unroll
            for (int rr = 0; rr < 4; ++rr) {
              int q = wr * 32 + qi * 16 + hh * 4 + rr;
              int kcol = ni * 16 + lq;
              Ps[q * 64 + ((((kcol >> 3) ^ (q & 7)) << 3) | (kcol & 7))] =
                  pbv[qi][ni][rr];
            }
      }
      SYNCB();                               // phase barrier B
    }

    // inv-rowsums -> LDS for the PV waves
    #pragma unroll
    for (int qi = 0; qi < 2; ++qi)
      #pragma unroll
      for (int rr = 0; rr < 4; ++rr) {
        float s = runsum[qi][rr];
        s += __shfl_xor(s, 1, 64);
        s += __shfl_xor(s, 2, 64);
        s += __shfl_xor(s, 4, 64);
        s += __shfl_xor(s, 8, 64);
        if (lq == 0) rs[wr * 32 + qi * 16 + hh * 4 + rr] = 1.f / s;
      }
    SYNCB();                                 // final barrier
  } else {
    // ---------------- PV consumer ----------------
    f32x4 oacc[8][4];
    #pragma unroll
    for (int qi = 0; qi < 8; ++qi)
      #pragma unroll
      for (int nj = 0; nj < 4; ++nj) oacc[qi][nj] = zero;

    #pragma unroll 1
    for (int p = 0; p <= 16; ++p) {
      if (p <= 15) stageV(p, p & 1);
      if (p <= 14) stageK(p + 1, (p + 1) & 1);
      if (p >= 1) {
        const u16* Vc = Vs[(p - 1) & 1];
        #pragma unroll
        for (int kk2 = 0; kk2 < 2; ++kk2) {
          bf16x8 pa[8];
          #pragma unroll
          for (int qi = 0; qi < 8; ++qi) {
            int r = qi * 16 + lq;
            pa[qi] = *reinterpret_cast<const bf16x8*>(
                &Ps[r * 64 + (((kk2 * 4 + hh) ^ (r & 7)) << 3)]);
          }
          bf16x8 vf[4];
          #pragma unroll
          for (int nj = 0; nj < 4; ++nj) {
            int n = wr * 64 + nj * 16 + lq;
            vf[nj] = *reinterpret_cast<const bf16x8*>(
                &Vc[n * 64 + (((kk2 * 4 + hh) ^ (n & 7)) << 3)]);
          }
          __builtin_amdgcn_s_setprio(1);
          #pragma unroll
          for (int qi = 0; qi < 8; ++qi)
            #pragma unroll
            for (int nj = 0; nj < 4; ++nj)
              oacc[qi][nj] = __builtin_amdgcn_mfma_f32_16x16x32_bf16(
                  pa[qi], vf[nj], oacc[qi][nj], 0, 0, 0);
          __builtin_amdgcn_s_setprio(0);
        }
      }
      SYNCB();                               // phase barrier A
      SYNCB();                               // phase barrier B
    }

    SYNCB();                                 // final barrier (rowsums ready)
    float rinv[8][4];
    #pragma unroll
    for (int qi = 0; qi < 8; ++qi)
      #pragma unroll
      for (int rr = 0; rr < 4; ++rr)
        rinv[qi][rr] = rs[qi * 16 + hh * 4 + rr];
    u16* ob = o + ((size_t)(b << 10) + qt * 128) * 256;
    #pragma unroll
    for (int qi = 0; qi < 8; ++qi)
      #pragma unroll
      for (int nj = 0; nj < 4; ++nj)
        #pragma unroll
        for (int rr = 0; rr < 4; ++rr)
          ob[(size_t)(qi * 16 + hh * 4 + rr) * 256 + wr * 64 + nj * 16 + lq] =
              f2bf(oacc[qi][nj][rr] * rinv[qi][rr]);
  }
}

extern "C" void kernel_launch(void* const* d_in, const int* in_sizes, int n_in,
                              void* d_out, int out_size, void* d_ws, size_t ws_size,
                              hipStream_t stream) {
  const float* x     = (const float*)d_in[0];
  const float* gamma = (const float*)d_in[1];
  const float* beta  = (const float*)d_in[2];
  const float* Wkqv  = (const float*)d_in[3];
  const float* bkqv  = (const float*)d_in[4];
  const float* Wproj = (const float*)d_in[5];
  const float* bproj = (const float*)d_in[6];
  float* out = (float*)d_out;          // fp32 [32,256,32,32]

  // ---- workspace layout ----
  char* ws = (char*)d_ws;
  u16* Wkb    = (u16*)(ws + 4096);              // 196608 bf16 (BN-folded)
  u16* Wpb    = (u16*)(ws + 397312);            // 65536 bf16
  float* bkbf = (float*)(ws + 528384);          // 768 f32 (folded bias)
  float* bpbf = (float*)(ws + 531456);          // 256 f32
  float* ssum = (float*)(ws + 540672);          // 256 f32 (stat partials)
  float* qsum = (float*)(ws + 541696);          // 256 f32
  u16* qk   = (u16*)(ws + 1048576);             // [32768,512] bf16 = 32 MB
  u16* vt   = qk + (size_t)32768 * 512;         // [32,256,1024] bf16 = 16 MB
  u16* o_pv = vt + (size_t)32 * 256 * 1024;     // [32768,256] bf16 = 16 MB

  // 0. zero stat accumulators + BN partial stats (8 blocks/CU, HBM-saturating)
  hipMemsetAsync(ssum, 0, 2 * 256 * sizeof(float), stream);
  bn_stats_kernel<<<dim3(2048), dim3(256), 0, stream>>>(x, ssum, qsum);
  // 1. weight prep: finalize stats inline; W' = Wkqv*scl, b' = b + Wkqv.sft
  prep_w_kernel<<<dim3(1024), dim3(256), 0, stream>>>(
      Wkqv, bkqv, Wproj, bproj, gamma, beta, ssum, qsum, Wkb, bkbf, Wpb, bpbf);
  // 2. fused QKV GEMM on raw x (SW-pipelined, vectorized staging): qk + vt
  qkv_fused_kernel<<<dim3(768), dim3(256), 0, stream>>>(
      x, Wkb, bkbf, qk, vt);
  // 3. fused attention (wave-specialized, round-6 proven): o_pv (bf16)
  attn_kernel<<<dim3(256), dim3(512), 0, stream>>>(qk, vt, o_pv);
  // 4. proj + residual (SW-pipelined): out = (o_pv @ Wp^T + bp)^T + x
  proj_kernel<<<dim3(256, 2), dim3(256), 0, stream>>>(
      o_pv, Wpb, bpbf, x, out);
}